// Round 2
// baseline (756.927 us; speedup 1.0000x reference)
//
#include <hip/hip_runtime.h>

// BKT 2-state HMM forward-backward, single-HBM-pass chunked scan.
// B=8192 chains, T=1024. NC=64 chunks of KC=16 steps; GG=4 chains/block.
// Phase 1: read obs/corr ONCE; stage obs in LDS (transposed, conflict-free);
//          pack y into a 16-bit register mask; build fwd composite F only.
//          (Bwd composite is free: Bw suffix == L^T * (F^T suffix), since
//           L^T applied to the zero log-vector is zero — columns of L are
//           normalized.)
// Phase 2: branchless unified scan — lane 0 fwd prefix, lane 1 bwd suffix,
//          running concurrently (no divergent serialization).
// Phase 3a: forward replay from LDS obs; state posteriors kept in registers
//           (32 floats) AND streamed to out1 — never re-read from HBM.
// Phase 3b: backward replay + smoothed from registers/LDS only.
// All output stores nontemporal (write-once streams, keep L2 clean).

#define BB 8192
#define TT 1024
#define KC 16               // steps per chunk
#define NC (TT / KC)        // 64 chunks per chain
#define GG 4                // chains per block (1 chain per wave)
#define NTHREADS (GG * NC)  // 256

typedef float floatx4 __attribute__((ext_vector_type(4)));

__device__ __forceinline__ float softplusf(float x) {
    return fmaxf(x, 0.0f) + __logf(1.0f + __expf(-fabsf(x)));
}
__device__ __forceinline__ float lse2(float a, float b) {
    float m = fmaxf(a, b);
    return m + __logf(1.0f + __expf(-fabsf(a - b)));
}
__device__ __forceinline__ void nt_store4(float2* base, float a, float b,
                                          float c, float d) {
    floatx4 v = {a, b, c, d};
    __builtin_nontemporal_store(v, (floatx4*)base);
}

__global__ __launch_bounds__(NTHREADS, 4) void bkt_kernel(
        const int* __restrict__ corr,
        const float* __restrict__ dyn,
        const float* __restrict__ obs,
        float* __restrict__ out) {
    // [g][steppair][chunk] -> lane stride 16B, b128 reads/writes conflict-free
    __shared__ float4 sObs4[GG][KC / 2][NC];  // 32 KB
    __shared__ float4 sF[GG][NC];             // 4 KB   fwd chunk composites
    __shared__ float2 sA[GG][NC];             // 2 KB   alpha at chunk entry
    __shared__ float2 sBe[GG][NC];            // 2 KB   beta at chunk end

    const int tid = threadIdx.x;
    const int g = tid >> 6;          // chain within block == wave id
    const int c = tid & (NC - 1);    // chunk index == lane
    const int b = blockIdx.x * GG + g;

    const float d0 = dyn[b * 3 + 0];
    const float d1 = dyn[b * 3 + 1];
    const float sd0 = softplusf(d0), sd1 = softplusf(d1);
    // log_t[i][j]: column-softmax of [[0,d1],[d0,0]]  (lse over i of each col = 0)
    const float lt00 = -sd0, lt10 = d0 - sd0, lt01 = d1 - sd1, lt11 = -sd1;

    const long long S = (long long)BB * TT;
    const long long cb = (long long)b * TT + c * KC;  // chunk base (float2 idx)
    const float2* obs2 = (const float2*)obs;
    float2* out0 = (float2*)out;       // pred logprobs
    float2* out1 = out0 + S;           // state posteriors (log-joint)
    float2* out2 = out1 + S;           // smoothed

    // ---------------- Phase 1: stage + fwd composite only --------------------
    unsigned ybits = 0;
    {
        const float4* op = (const float4*)(obs2 + cb);
        const int4* yp = (const int4*)(corr + cb);
        float F00, F01, F10, F11;
        #pragma unroll
        for (int h = 0; h < 2; ++h) {
            float4 o4[4] = {op[4 * h + 0], op[4 * h + 1], op[4 * h + 2], op[4 * h + 3]};
            int4 ya = yp[2 * h + 0], yb = yp[2 * h + 1];
            int ys[8] = {ya.x, ya.y, ya.z, ya.w, yb.x, yb.y, yb.z, yb.w};
            float ox[8] = {o4[0].x, o4[0].z, o4[1].x, o4[1].z, o4[2].x, o4[2].z, o4[3].x, o4[3].z};
            float oy[8] = {o4[0].y, o4[0].w, o4[1].y, o4[1].w, o4[2].y, o4[2].w, o4[3].y, o4[3].w};
            #pragma unroll
            for (int s = 0; s < 8; ++s) {
                const int q = h * 8 + s;
                if (s & 1)  // write step pair (q-1, q) as one b128
                    sObs4[g][q >> 1][c] = make_float4(ox[s - 1], oy[s - 1], ox[s], oy[s]);
                ybits |= (unsigned)(ys[s] & 1) << q;
                float sp0 = softplusf(ox[s]), sp1 = softplusf(oy[s]);
                float py0 = ys[s] ? (ox[s] - sp0) : (-sp0);
                float py1 = ys[s] ? (-sp1) : (oy[s] - sp1);
                float N00 = py0 + lt00, N01 = py1 + lt01;
                float N10 = py0 + lt10, N11 = py1 + lt11;
                if (q == 0) {
                    F00 = N00; F01 = N01; F10 = N10; F11 = N11;
                } else {
                    float a_ = lse2(N00 + F00, N01 + F10);
                    float b_ = lse2(N00 + F01, N01 + F11);
                    float c_ = lse2(N10 + F00, N11 + F10);
                    float d_ = lse2(N10 + F01, N11 + F11);
                    F00 = a_; F01 = b_; F10 = c_; F11 = d_;
                }
            }
        }
        sF[g][c] = make_float4(F00, F01, F10, F11);
    }
    __syncthreads();

    // ---------------- Phase 2: unified fwd/bwd chunk scan ---------------------
    // lane 0: alpha prefix (a' = F*a).  lane 1: suffix w' = F^T*w,
    // betaEnd = L^T*w.  Same instruction stream, selects only.
    if (c < 2) {
        const int r = c;
        float v0, v1;
        if (r == 0) {
            const float d2 = dyn[b * 3 + 2];
            const float sd2 = softplusf(d2);
            v0 = -sd2; v1 = d2 - sd2;
            sA[g][0] = make_float2(v0, v1);
        } else {
            v0 = 0.0f; v1 = 0.0f;
            sBe[g][NC - 1] = make_float2(0.0f, 0.0f);
        }
        for (int i = 0; i < NC - 1; ++i) {
            const int idx = r ? (NC - 1 - i) : i;
            float4 f = sF[g][idx];
            float m01 = r ? f.z : f.y;   // transpose select for bwd
            float m10 = r ? f.y : f.z;
            float nv0 = lse2(f.x + v0, m01 + v1);
            float nv1 = lse2(m10 + v0, f.w + v1);
            v0 = nv0; v1 = nv1;
            float e0 = lse2(lt00 + v0, lt10 + v1);  // L^T * w (used by bwd lane)
            float e1 = lse2(lt01 + v0, lt11 + v1);
            float2 outv = r ? make_float2(e0, e1) : make_float2(v0, v1);
            float2* dst = r ? &sBe[g][idx - 1] : &sA[g][i + 1];
            *dst = outv;
        }
    }
    __syncthreads();

    // ---------------- Phase 3a: forward replay (obs from LDS) ----------------
    float w1r[2 * KC];  // state posteriors, kept for phase 3b
    {
        float2 av = sA[g][c];
        float a0 = av.x, a1 = av.y;
        #pragma unroll
        for (int h = 0; h < 2; ++h) {
            float wo[16];
            #pragma unroll
            for (int p = 0; p < 4; ++p) {
                float4 ov = sObs4[g][h * 4 + p][c];
                #pragma unroll
                for (int r2 = 0; r2 < 2; ++r2) {
                    const int l = p * 2 + r2;
                    const int q = h * 8 + l;
                    float ox = r2 ? ov.z : ov.x;
                    float oy = r2 ? ov.w : ov.y;
                    float sp0 = softplusf(ox), sp1 = softplusf(oy);
                    float lo00 = -sp0,      lo01 = ox - sp0;
                    float lo10 = oy - sp1,  lo11 = -sp1;
                    float p0 = lse2(lo00 + a0, lo10 + a1);
                    float p1 = lse2(lo01 + a0, lo11 + a1);
                    float n = lse2(p0, p1);
                    wo[2 * l] = p0 - n; wo[2 * l + 1] = p1 - n;
                    int y = (ybits >> q) & 1;
                    float py0 = y ? lo01 : lo00;
                    float py1 = y ? lo11 : lo10;
                    float s0 = py0 + a0, s1 = py1 + a1;
                    w1r[2 * q] = s0; w1r[2 * q + 1] = s1;
                    a0 = lse2(s0 + lt00, s1 + lt01);
                    a1 = lse2(s0 + lt10, s1 + lt11);
                }
            }
            #pragma unroll
            for (int k = 0; k < 4; ++k) {
                nt_store4(out0 + cb + h * 8 + 2 * k,
                          wo[4 * k], wo[4 * k + 1], wo[4 * k + 2], wo[4 * k + 3]);
                nt_store4(out1 + cb + h * 8 + 2 * k,
                          w1r[16 * h + 4 * k], w1r[16 * h + 4 * k + 1],
                          w1r[16 * h + 4 * k + 2], w1r[16 * h + 4 * k + 3]);
            }
        }
    }

    // ---------------- Phase 3b: backward replay + smoothed -------------------
    {
        float2 bv = sBe[g][c];
        float be0 = bv.x, be1 = bv.y;
        #pragma unroll
        for (int h = 1; h >= 0; --h) {
            float w2[16];
            #pragma unroll
            for (int p = 3; p >= 0; --p) {
                float4 ov = sObs4[g][h * 4 + p][c];
                #pragma unroll
                for (int r2 = 1; r2 >= 0; --r2) {
                    const int l = p * 2 + r2;
                    const int q = h * 8 + l;
                    // smoothed at t uses current beta (aligned at t)
                    float s0 = w1r[2 * q] + be0, s1 = w1r[2 * q + 1] + be1;
                    float n = lse2(s0, s1);
                    w2[2 * l] = s0 - n; w2[2 * l + 1] = s1 - n;
                    // advance beta to t-1
                    float ox = r2 ? ov.z : ov.x;
                    float oy = r2 ? ov.w : ov.y;
                    float sp0 = softplusf(ox), sp1 = softplusf(oy);
                    int y = (ybits >> q) & 1;
                    float py0 = y ? (ox - sp0) : (-sp0);
                    float py1 = y ? (-sp1) : (oy - sp1);
                    float nb0 = lse2(py0 + be0 + lt00, py1 + be1 + lt10);
                    float nb1 = lse2(py0 + be0 + lt01, py1 + be1 + lt11);
                    be0 = nb0; be1 = nb1;
                }
            }
            #pragma unroll
            for (int k = 0; k < 4; ++k)
                nt_store4(out2 + cb + h * 8 + 2 * k,
                          w2[4 * k], w2[4 * k + 1], w2[4 * k + 2], w2[4 * k + 3]);
        }
    }
}

extern "C" void kernel_launch(void* const* d_in, const int* in_sizes, int n_in,
                              void* d_out, int out_size, void* d_ws, size_t ws_size,
                              hipStream_t stream) {
    const int*   corr = (const int*)d_in[0];
    const float* dyn  = (const float*)d_in[1];
    const float* obs  = (const float*)d_in[2];
    float* out = (float*)d_out;

    dim3 block(NTHREADS);            // 256 = 4 chains x 64 chunks
    dim3 grid(BB / GG);              // 2048 blocks
    bkt_kernel<<<grid, block, 0, stream>>>(corr, dyn, obs, out);
}

// Round 3
// 360.669 us; speedup vs baseline: 2.0987x; 2.0987x over previous
//
#include <hip/hip_runtime.h>

// BKT 2-state HMM forward-backward, single-HBM-pass, coalesced staged stores.
// B=8192 chains, T=1024. NC=64 chunks of KC=16 steps; GG=4 chains/block
// (one chain per wave; lane == chunk).
// - obs/corr read ONCE from HBM into registers; softplus cached (computed 1x).
// - Fwd chunk composites -> LDS; bwd composite derived analytically
//   (Bw suffix == L^T * (F^T suffix) since columns of L are lse-normalized).
// - Outputs staged through a 32 KB LDS buffer (XOR-swizzled, conflict-free)
//   and written as full contiguous 4 KB lines per wave-instruction with
//   nontemporal stores. This kills the 2.75x write amplification of the
//   chunk-per-lane strided store pattern.

#define BB 8192
#define TT 1024
#define KC 16               // steps per chunk
#define NC (TT / KC)        // 64 chunks per chain == lanes per wave
#define GG 4                // chains per block (1 per wave)
#define NTHREADS (GG * NC)  // 256

typedef float floatx4 __attribute__((ext_vector_type(4)));

__device__ __forceinline__ float softplusf(float x) {
    return fmaxf(x, 0.0f) + __logf(1.0f + __expf(-fabsf(x)));
}
__device__ __forceinline__ float lse2(float a, float b) {
    float m = fmaxf(a, b);
    return m + __logf(1.0f + __expf(-fabsf(a - b)));
}

// Coalesced writeout of one staged stream: 256 threads x 8 iters x 16 B,
// consecutive lanes -> consecutive 16 B (full-line NT stores).
__device__ __forceinline__ void writeout_stream(
        const floatx4 (*st)[NC][8], float2* dst, long long bBase, int tid) {
    #pragma unroll
    for (int i = 0; i < 8; ++i) {
        int L = i * NTHREADS + tid;   // 0..2047 float4 slots per block-stream
        int g2 = L >> 9;              // chain within block (512 float4/chain)
        int pos = L & 511;            // float4 index within chain
        int c2 = pos >> 3, k2 = pos & 7;
        floatx4 v = st[g2][c2][k2 ^ (c2 & 7)];
        __builtin_nontemporal_store(
            v, (floatx4*)(dst + (bBase + g2) * TT + pos * 2));
    }
}

__global__ __launch_bounds__(NTHREADS, 4) void bkt_kernel(
        const int* __restrict__ corr,
        const float* __restrict__ dyn,
        const float* __restrict__ obs,
        float* __restrict__ out) {
    __shared__ floatx4 st[GG][NC][8];  // 32 KB staging (one stream at a time)
    __shared__ float4 sF[GG][NC];      // 4 KB fwd chunk composites
    __shared__ float2 sA[GG][NC];      // 2 KB alpha at chunk entry
    __shared__ float2 sBe[GG][NC];     // 2 KB beta at chunk end

    const int tid = threadIdx.x;
    const int g = tid >> 6;          // chain within block == wave id
    const int c = tid & (NC - 1);    // chunk index == lane
    const int b = blockIdx.x * GG + g;

    const float d0 = dyn[b * 3 + 0];
    const float d1 = dyn[b * 3 + 1];
    const float sd0 = softplusf(d0), sd1 = softplusf(d1);
    // log_t[i][j]: column-softmax of [[0,d1],[d0,0]] (lse over i of col = 0)
    const float lt00 = -sd0, lt10 = d0 - sd0, lt01 = d1 - sd1, lt11 = -sd1;

    const long long S = (long long)BB * TT;
    const long long cb = (long long)b * TT + c * KC;  // chunk base (float2 idx)
    const float2* obs2 = (const float2*)obs;
    float2* out0 = (float2*)out;       // pred logprobs
    float2* out1 = out0 + S;           // state posteriors (log-joint)
    float2* out2 = out1 + S;           // smoothed

    // ---------------- Phase 1: load to regs + fwd composite ------------------
    float ox[16], oy[16], sp0a[16], sp1a[16];
    unsigned ybits = 0;
    {
        const float4* op = (const float4*)(obs2 + cb);
        const int4* yp = (const int4*)(corr + cb);
        #pragma unroll
        for (int j = 0; j < 8; ++j) {
            float4 o4 = op[j];
            ox[2 * j] = o4.x; oy[2 * j] = o4.y;
            ox[2 * j + 1] = o4.z; oy[2 * j + 1] = o4.w;
        }
        #pragma unroll
        for (int j = 0; j < 4; ++j) {
            int4 y4 = yp[j];
            ybits |= (unsigned)(y4.x & 1) << (4 * j + 0);
            ybits |= (unsigned)(y4.y & 1) << (4 * j + 1);
            ybits |= (unsigned)(y4.z & 1) << (4 * j + 2);
            ybits |= (unsigned)(y4.w & 1) << (4 * j + 3);
        }
        float F00, F01, F10, F11;
        #pragma unroll
        for (int q = 0; q < 16; ++q) {
            float sp0 = softplusf(ox[q]), sp1 = softplusf(oy[q]);
            sp0a[q] = sp0; sp1a[q] = sp1;
            int y = (ybits >> q) & 1;
            float py0 = y ? (ox[q] - sp0) : (-sp0);
            float py1 = y ? (-sp1) : (oy[q] - sp1);
            float N00 = py0 + lt00, N01 = py1 + lt01;
            float N10 = py0 + lt10, N11 = py1 + lt11;
            if (q == 0) {
                F00 = N00; F01 = N01; F10 = N10; F11 = N11;
            } else {
                float a_ = lse2(N00 + F00, N01 + F10);
                float b_ = lse2(N00 + F01, N01 + F11);
                float c_ = lse2(N10 + F00, N11 + F10);
                float d_ = lse2(N10 + F01, N11 + F11);
                F00 = a_; F01 = b_; F10 = c_; F11 = d_;
            }
        }
        sF[g][c] = make_float4(F00, F01, F10, F11);
    }
    __syncthreads();

    // ---------------- Phase 2: unified fwd/bwd chunk scan ---------------------
    // lane 0: alpha prefix (a' = F*a).  lane 1: suffix w' = F^T*w,
    // betaEnd = L^T*w.  Same instruction stream, selects only.
    if (c < 2) {
        const int r = c;
        float v0, v1;
        if (r == 0) {
            const float d2 = dyn[b * 3 + 2];
            const float sd2 = softplusf(d2);
            v0 = -sd2; v1 = d2 - sd2;
            sA[g][0] = make_float2(v0, v1);
        } else {
            v0 = 0.0f; v1 = 0.0f;
            sBe[g][NC - 1] = make_float2(0.0f, 0.0f);
        }
        for (int i = 0; i < NC - 1; ++i) {
            const int idx = r ? (NC - 1 - i) : i;
            float4 f = sF[g][idx];
            float m01 = r ? f.z : f.y;   // transpose select for bwd
            float m10 = r ? f.y : f.z;
            float nv0 = lse2(f.x + v0, m01 + v1);
            float nv1 = lse2(m10 + v0, f.w + v1);
            v0 = nv0; v1 = nv1;
            float e0 = lse2(lt00 + v0, lt10 + v1);  // L^T * w (bwd lane)
            float e1 = lse2(lt01 + v0, lt11 + v1);
            float2 outv = r ? make_float2(e0, e1) : make_float2(v0, v1);
            float2* dst = r ? &sBe[g][idx - 1] : &sA[g][i + 1];
            *dst = outv;
        }
    }
    __syncthreads();

    // ---------------- Phase 3a: forward replay (posteriors -> st) ------------
    float wo[32];
    {
        float2 av = sA[g][c];
        float a0 = av.x, a1 = av.y;
        float ps0 = 0.0f, ps1 = 0.0f;
        #pragma unroll
        for (int q = 0; q < 16; ++q) {
            float lo00 = -sp0a[q],            lo01 = ox[q] - sp0a[q];
            float lo10 = oy[q] - sp1a[q],     lo11 = -sp1a[q];
            float p0 = lse2(lo00 + a0, lo10 + a1);
            float p1 = lse2(lo01 + a0, lo11 + a1);
            float n = lse2(p0, p1);
            wo[2 * q] = p0 - n; wo[2 * q + 1] = p1 - n;
            int y = (ybits >> q) & 1;
            float py0 = y ? lo01 : lo00;
            float py1 = y ? lo11 : lo10;
            float s0 = py0 + a0, s1 = py1 + a1;
            ox[q] = py0; oy[q] = py1;   // reuse obs regs as py for phase 3b
            if (q & 1) {
                floatx4 v = {ps0, ps1, s0, s1};
                st[g][c][(q >> 1) ^ (c & 7)] = v;
            } else { ps0 = s0; ps1 = s1; }
            a0 = lse2(s0 + lt00, s1 + lt01);
            a1 = lse2(s0 + lt10, s1 + lt11);
        }
    }
    __syncthreads();   // st fully holds posteriors

    const long long bBase = (long long)blockIdx.x * GG;
    writeout_stream(st, out1, bBase, tid);   // stores issue, overlap phase 3b

    // ---------------- Phase 3b: backward replay + smoothed -------------------
    float w2[32];
    {
        float2 bv = sBe[g][c];
        float be0 = bv.x, be1 = bv.y;
        floatx4 pr;
        #pragma unroll
        for (int q = 15; q >= 0; --q) {
            if (q & 1) pr = st[g][c][(q >> 1) ^ (c & 7)];  // own posterior pair
            float s0 = (q & 1) ? pr.z : pr.x;
            float s1 = (q & 1) ? pr.w : pr.y;
            float t0 = s0 + be0, t1 = s1 + be1;
            float n = lse2(t0, t1);
            w2[2 * q] = t0 - n; w2[2 * q + 1] = t1 - n;
            // advance beta to q-1 (py held in ox/oy)
            float nb0 = lse2(ox[q] + be0 + lt00, oy[q] + be1 + lt10);
            float nb1 = lse2(ox[q] + be0 + lt01, oy[q] + be1 + lt11);
            be0 = nb0; be1 = nb1;
        }
    }
    __syncthreads();   // all st readers done

    // ---------------- stage + writeout out0 ----------------------------------
    #pragma unroll
    for (int k = 0; k < 8; ++k) {
        floatx4 v = {wo[4 * k], wo[4 * k + 1], wo[4 * k + 2], wo[4 * k + 3]};
        st[g][c][k ^ (c & 7)] = v;
    }
    __syncthreads();
    writeout_stream(st, out0, bBase, tid);
    __syncthreads();

    // ---------------- stage + writeout out2 ----------------------------------
    #pragma unroll
    for (int k = 0; k < 8; ++k) {
        floatx4 v = {w2[4 * k], w2[4 * k + 1], w2[4 * k + 2], w2[4 * k + 3]};
        st[g][c][k ^ (c & 7)] = v;
    }
    __syncthreads();
    writeout_stream(st, out2, bBase, tid);
}

extern "C" void kernel_launch(void* const* d_in, const int* in_sizes, int n_in,
                              void* d_out, int out_size, void* d_ws, size_t ws_size,
                              hipStream_t stream) {
    const int*   corr = (const int*)d_in[0];
    const float* dyn  = (const float*)d_in[1];
    const float* obs  = (const float*)d_in[2];
    float* out = (float*)d_out;

    dim3 block(NTHREADS);            // 256 = 4 chains x 64 chunks
    dim3 grid(BB / GG);              // 2048 blocks
    bkt_kernel<<<grid, block, 0, stream>>>(corr, dyn, obs, out);
}

// Round 4
// 294.539 us; speedup vs baseline: 2.5699x; 1.2245x over previous
//
#include <hip/hip_runtime.h>

// BKT 2-state HMM forward-backward. Zero-barrier, zero-spill design.
// B=8192 chains, T=1024. One chain per wave (64 lanes = 64 chunks of KC=16).
// GG=4 chains/block (256 threads), grid 2048.
//
// Per wave (fully independent, NO __syncthreads in the kernel):
//  P1: obs/corr -> regs (single HBM read); per-lane chunk composite F.
//  P2: dual Kogge-Stone scan over lanes (log-semiring 2x2 matrix compose,
//      __shfl_up for alpha prefix, __shfl_down for beta suffix). The beta
//      suffix needs only F^T: Bw-suffix == L^T * (F^T-suffix) since L's
//      columns are lse-normalized.
//  P3: backward pass, betas stored to registers bst[32] (no outputs).
//  P4: forward pass emits ALL THREE outputs per step (pred, posterior,
//      smoothed = posterior + bst). Pairs staged to swizzled LDS half-
//      buffers; after each 8-step half, the wave writes its own chain's
//      3 half-streams as full-64B-line nontemporal stores.

#define BB 8192
#define TT 1024
#define KC 16               // steps per chunk
#define NC 64               // chunks per chain == lanes per wave
#define GG 4                // chains per block (1 per wave)
#define NTHREADS (GG * NC)  // 256
#define NEGI (-1.0e30f)     // log-domain "-inf" (safe under adds)

typedef float floatx4 __attribute__((ext_vector_type(4)));

__device__ __forceinline__ float softplusf(float x) {
    return fmaxf(x, 0.0f) + __logf(1.0f + __expf(-fabsf(x)));
}
__device__ __forceinline__ float lse2(float a, float b) {
    float m = fmaxf(a, b);
    return m + __logf(1.0f + __expf(-fabsf(a - b)));
}

__global__ __launch_bounds__(NTHREADS, 3) void bkt_kernel(
        const int* __restrict__ corr,
        const float* __restrict__ dyn,
        const float* __restrict__ obs,
        float* __restrict__ out) {
    // Half-chunk staging: [chain][chunk][4 pair-slots], swizzled. 3 x 16 KB.
    __shared__ floatx4 st0[GG][NC][4];
    __shared__ floatx4 st1[GG][NC][4];
    __shared__ floatx4 st2[GG][NC][4];

    const int tid = threadIdx.x;
    const int g = tid >> 6;          // chain within block == wave id
    const int c = tid & (NC - 1);    // chunk index == lane
    const int b = blockIdx.x * GG + g;

    const float d0 = dyn[b * 3 + 0];
    const float d1 = dyn[b * 3 + 1];
    const float d2 = dyn[b * 3 + 2];
    const float sd0 = softplusf(d0), sd1 = softplusf(d1);
    // log_t[i][j]: column-softmax of [[0,d1],[d0,0]] (lse over i of col = 0)
    const float lt00 = -sd0, lt10 = d0 - sd0, lt01 = d1 - sd1, lt11 = -sd1;

    const long long cb = (long long)b * TT + c * KC;  // chunk base (float2 idx)
    const float2* obs2 = (const float2*)obs;
    const long long S4 = (long long)BB * 512;         // float4 per stream
    floatx4* o0 = (floatx4*)out;        // pred logprobs
    floatx4* o1 = o0 + S4;              // state posteriors (log-joint)
    floatx4* o2 = o1 + S4;              // smoothed

    // ---------------- P1: load to regs + fwd chunk composite -----------------
    float ox[16], oy[16], sp0a[16], sp1a[16];
    unsigned ybits = 0;
    float F00, F01, F10, F11;
    {
        const float4* op = (const float4*)(obs2 + cb);
        const int4* yp = (const int4*)(corr + cb);
        #pragma unroll
        for (int j = 0; j < 8; ++j) {
            float4 o4 = op[j];
            ox[2 * j] = o4.x; oy[2 * j] = o4.y;
            ox[2 * j + 1] = o4.z; oy[2 * j + 1] = o4.w;
        }
        #pragma unroll
        for (int j = 0; j < 4; ++j) {
            int4 y4 = yp[j];
            ybits |= (unsigned)(y4.x & 1) << (4 * j + 0);
            ybits |= (unsigned)(y4.y & 1) << (4 * j + 1);
            ybits |= (unsigned)(y4.z & 1) << (4 * j + 2);
            ybits |= (unsigned)(y4.w & 1) << (4 * j + 3);
        }
        #pragma unroll
        for (int q = 0; q < 16; ++q) {
            float sp0 = softplusf(ox[q]), sp1 = softplusf(oy[q]);
            sp0a[q] = sp0; sp1a[q] = sp1;
            int y = (ybits >> q) & 1;
            float py0 = y ? (ox[q] - sp0) : (-sp0);
            float py1 = y ? (-sp1) : (oy[q] - sp1);
            float N00 = py0 + lt00, N01 = py1 + lt01;
            float N10 = py0 + lt10, N11 = py1 + lt11;
            if (q == 0) {
                F00 = N00; F01 = N01; F10 = N10; F11 = N11;
            } else {   // F := N * F
                float a_ = lse2(N00 + F00, N01 + F10);
                float b_ = lse2(N00 + F01, N01 + F11);
                float c_ = lse2(N10 + F00, N11 + F10);
                float d_ = lse2(N10 + F01, N11 + F11);
                F00 = a_; F01 = b_; F10 = c_; F11 = d_;
            }
        }
    }

    // ---------------- P2: dual Kogge-Stone scan over lanes -------------------
    // Fwd: G_c = F_c * F_{c-1} * ... * F_0 (inclusive prefix).
    float G00 = F00, G01 = F01, G10 = F10, G11 = F11;
    // Bwd: H_c = F^T_{c+1} * F^T_{c+2} * ... (suffix); init F^T from lane c+1.
    float H00 = __shfl_down(F00, 1);
    float H01 = __shfl_down(F10, 1);   // transpose while shuffling
    float H10 = __shfl_down(F01, 1);
    float H11 = __shfl_down(F11, 1);
    if (c == NC - 1) { H00 = 0.0f; H01 = NEGI; H10 = NEGI; H11 = 0.0f; }
    #pragma unroll
    for (int dlv = 0; dlv < 6; ++dlv) {
        const int off = 1 << dlv;
        float u00 = __shfl_up(G00, off), u01 = __shfl_up(G01, off);
        float u10 = __shfl_up(G10, off), u11 = __shfl_up(G11, off);
        float g00 = lse2(G00 + u00, G01 + u10);
        float g01 = lse2(G00 + u01, G01 + u11);
        float g10 = lse2(G10 + u00, G11 + u10);
        float g11 = lse2(G10 + u01, G11 + u11);
        bool dg = (c >= off);
        G00 = dg ? g00 : G00; G01 = dg ? g01 : G01;
        G10 = dg ? g10 : G10; G11 = dg ? g11 : G11;
        float v00 = __shfl_down(H00, off), v01 = __shfl_down(H01, off);
        float v10 = __shfl_down(H10, off), v11 = __shfl_down(H11, off);
        float h00 = lse2(H00 + v00, H01 + v10);
        float h01 = lse2(H00 + v01, H01 + v11);
        float h10 = lse2(H10 + v00, H11 + v10);
        float h11 = lse2(H10 + v01, H11 + v11);
        bool dh = (c + off < NC);
        H00 = dh ? h00 : H00; H01 = dh ? h01 : H01;
        H10 = dh ? h10 : H10; H11 = dh ? h11 : H11;
    }
    // alpha at chunk entry: P_{c-1} * a_init (lane 0: a_init).
    const float sd2 = softplusf(d2);
    const float ai0 = -sd2, ai1 = d2 - sd2;
    float P00 = __shfl_up(G00, 1), P01 = __shfl_up(G01, 1);
    float P10 = __shfl_up(G10, 1), P11 = __shfl_up(G11, 1);
    float t0 = lse2(P00 + ai0, P01 + ai1);
    float t1 = lse2(P10 + ai0, P11 + ai1);
    float a0 = (c == 0) ? ai0 : t0;
    float a1 = (c == 0) ? ai1 : t1;
    // beta at chunk end: L^T * (row-lse of H)   (H * 0vec = row-lse)
    float w0 = lse2(H00, H01);
    float w1 = lse2(H10, H11);
    float be0 = lse2(lt00 + w0, lt10 + w1);
    float be1 = lse2(lt01 + w0, lt11 + w1);

    // ---------------- P3: backward pass, betas -> registers ------------------
    float bst0[16], bst1[16];
    {
        float bb0 = be0, bb1 = be1;
        #pragma unroll
        for (int q = 15; q >= 0; --q) {
            bst0[q] = bb0; bst1[q] = bb1;
            int y = (ybits >> q) & 1;
            float py0 = y ? (ox[q] - sp0a[q]) : (-sp0a[q]);
            float py1 = y ? (-sp1a[q]) : (oy[q] - sp1a[q]);
            float nb0 = lse2(py0 + bb0 + lt00, py1 + bb1 + lt10);
            float nb1 = lse2(py0 + bb0 + lt01, py1 + bb1 + lt11);
            bb0 = nb0; bb1 = nb1;
        }
    }

    // ---------------- P4: forward pass, 3 outputs, per-half writeout ---------
    const long long bb4 = (long long)b * 512;   // float4 base of this chain
    const int kswz = (c >> 1) & 3;
    #pragma unroll
    for (int h = 0; h < 2; ++h) {
        float e0a, e1a, e0b, e1b, e0c, e1c;   // even-step saved pairs
        #pragma unroll
        for (int l = 0; l < 8; ++l) {
            const int q = h * 8 + l;
            float lo00 = -sp0a[q],        lo01 = ox[q] - sp0a[q];
            float lo10 = oy[q] - sp1a[q], lo11 = -sp1a[q];
            float p0 = lse2(lo00 + a0, lo10 + a1);
            float p1 = lse2(lo01 + a0, lo11 + a1);
            float n = lse2(p0, p1);
            float wo0 = p0 - n, wo1 = p1 - n;
            int y = (ybits >> q) & 1;
            float py0 = y ? lo01 : lo00;
            float py1 = y ? lo11 : lo10;
            float s0 = py0 + a0, s1 = py1 + a1;
            float u0 = s0 + bst0[q], u1 = s1 + bst1[q];
            float nn = lse2(u0, u1);
            float w20 = u0 - nn, w21 = u1 - nn;
            a0 = lse2(s0 + lt00, s1 + lt01);
            a1 = lse2(s0 + lt10, s1 + lt11);
            if (l & 1) {
                int kk = (l >> 1) ^ kswz;
                st0[g][c][kk] = (floatx4){e0a, e1a, wo0, wo1};
                st1[g][c][kk] = (floatx4){e0b, e1b, s0, s1};
                st2[g][c][kk] = (floatx4){e0c, e1c, w20, w21};
            } else {
                e0a = wo0; e1a = wo1; e0b = s0; e1b = s1; e0c = w20; e1c = w21;
            }
        }
        // wave-local coalesced writeout of half h (full 64B lines, NT)
        #pragma unroll
        for (int i = 0; i < 4; ++i) {
            int flat = i * 64 + c;            // 0..255 f4 of this half-stream
            int c2 = flat >> 2, k2 = flat & 3;
            int kk = k2 ^ ((c2 >> 1) & 3);
            long long adr = bb4 + (long long)(c2 * 8 + k2 + 4 * h);
            __builtin_nontemporal_store(st0[g][c2][kk], o0 + adr);
            __builtin_nontemporal_store(st1[g][c2][kk], o1 + adr);
            __builtin_nontemporal_store(st2[g][c2][kk], o2 + adr);
        }
    }
}

extern "C" void kernel_launch(void* const* d_in, const int* in_sizes, int n_in,
                              void* d_out, int out_size, void* d_ws, size_t ws_size,
                              hipStream_t stream) {
    const int*   corr = (const int*)d_in[0];
    const float* dyn  = (const float*)d_in[1];
    const float* obs  = (const float*)d_in[2];
    float* out = (float*)d_out;

    dim3 block(NTHREADS);            // 256 = 4 chains x 64 chunks
    dim3 grid(BB / GG);              // 2048 blocks
    bkt_kernel<<<grid, block, 0, stream>>>(corr, dyn, obs, out);
}